// Round 1
// baseline (3655.748 us; speedup 1.0000x reference)
//
#include <hip/hip_runtime.h>

#define D_MODEL 1024
#define NUM_HEADS 16
#define D_K 64
#define BATCH 2
#define SEQ 2048
#define TQ 4

// ---------------------------------------------------------------------------
// Tiled fp32 GEMM: C[M,1024] = A[M,1024] @ W[1024,1024] + bias[1024]
// 64x64 tile per 256-thread block, 4x4 micro-tile per thread, K-tile = 16.
// ---------------------------------------------------------------------------
__global__ __launch_bounds__(256)
void gemm_bias_kernel(const float* __restrict__ A, const float* __restrict__ W,
                      const float* __restrict__ bias, float* __restrict__ C) {
    __shared__ float As[16][64];   // [k][row] (transposed for broadcast reads)
    __shared__ float Bs[16][64];   // [k][col]

    const int tid = threadIdx.x;
    const int tx = tid & 15;        // 0..15 -> col group
    const int ty = tid >> 4;        // 0..15 -> row group
    const int rowBase = blockIdx.y * 64;
    const int colBase = blockIdx.x * 64;

    // staging-load indices
    const int ar = tid >> 2;            // 0..63  A-tile row
    const int ac = (tid & 3) * 4;       // 0,4,8,12 A-tile k-offset
    const int br = tid >> 4;            // 0..15  W-tile k-row
    const int bc = (tid & 15) * 4;      // 0..60  W-tile col

    float acc[4][4] = {};

    for (int k0 = 0; k0 < D_MODEL; k0 += 16) {
        float4 av = *(const float4*)(A + (size_t)(rowBase + ar) * D_MODEL + k0 + ac);
        float4 bv = *(const float4*)(W + (size_t)(k0 + br) * D_MODEL + colBase + bc);
        __syncthreads();   // previous iteration's LDS reads must finish
        As[ac + 0][ar] = av.x;
        As[ac + 1][ar] = av.y;
        As[ac + 2][ar] = av.z;
        As[ac + 3][ar] = av.w;
        *(float4*)&Bs[br][bc] = bv;
        __syncthreads();
#pragma unroll
        for (int kk = 0; kk < 16; ++kk) {
            const float a0 = As[kk][ty * 4 + 0];
            const float a1 = As[kk][ty * 4 + 1];
            const float a2 = As[kk][ty * 4 + 2];
            const float a3 = As[kk][ty * 4 + 3];
            const float4 b = *(const float4*)&Bs[kk][tx * 4];
            acc[0][0] += a0 * b.x; acc[0][1] += a0 * b.y; acc[0][2] += a0 * b.z; acc[0][3] += a0 * b.w;
            acc[1][0] += a1 * b.x; acc[1][1] += a1 * b.y; acc[1][2] += a1 * b.z; acc[1][3] += a1 * b.w;
            acc[2][0] += a2 * b.x; acc[2][1] += a2 * b.y; acc[2][2] += a2 * b.z; acc[2][3] += a2 * b.w;
            acc[3][0] += a3 * b.x; acc[3][1] += a3 * b.y; acc[3][2] += a3 * b.z; acc[3][3] += a3 * b.w;
        }
    }

    const float4 bb = *(const float4*)(bias + colBase + tx * 4);
#pragma unroll
    for (int i = 0; i < 4; ++i) {
        float4 o;
        o.x = acc[i][0] + bb.x;
        o.y = acc[i][1] + bb.y;
        o.z = acc[i][2] + bb.z;
        o.w = acc[i][3] + bb.w;
        *(float4*)(C + (size_t)(rowBase + ty * 4 + i) * D_MODEL + colBase + tx * 4) = o;
    }
}

// ---------------------------------------------------------------------------
// Attention: one block per (b, h, 4 query rows).
// scores -> softmax (kept in LDS) -> write attn -> fused PV -> ctx
// ---------------------------------------------------------------------------
__global__ __launch_bounds__(256)
void attn_kernel(const float* __restrict__ Qp, const float* __restrict__ Kp,
                 const float* __restrict__ Vp, float* __restrict__ attn,
                 float* __restrict__ ctx) {
    const int b  = blockIdx.z;
    const int h  = blockIdx.y;
    const int q0 = blockIdx.x * TQ;
    const int tid = threadIdx.x;

    __shared__ float qv[TQ][64];
    __shared__ float sc[TQ][SEQ];      // un-normalized exp values
    __shared__ float red[TQ][256];
    __shared__ float mrow[TQ], srow[TQ];

    // load 4 query vectors (256 threads = 4*64 elements)
    {
        const int qq = tid >> 6, d = tid & 63;
        qv[qq][d] = Qp[((size_t)(b * SEQ + q0 + qq)) * D_MODEL + h * 64 + d];
    }
    __syncthreads();

    // ---- scores: each thread computes 8 k-columns for all TQ rows ----
    float loc[TQ][8];
    const float scale = 0.125f;   // 1/sqrt(64)
#pragma unroll
    for (int i = 0; i < 8; ++i) {
        const int kk = i * 256 + tid;
        const float* Kr = Kp + ((size_t)(b * SEQ + kk)) * D_MODEL + h * 64;
        float dot[TQ] = {0.f, 0.f, 0.f, 0.f};
#pragma unroll
        for (int d = 0; d < 64; d += 4) {
            const float4 kvv = *(const float4*)(Kr + d);
#pragma unroll
            for (int qq = 0; qq < TQ; ++qq) {
                dot[qq] += qv[qq][d] * kvv.x + qv[qq][d + 1] * kvv.y +
                           qv[qq][d + 2] * kvv.z + qv[qq][d + 3] * kvv.w;
            }
        }
#pragma unroll
        for (int qq = 0; qq < TQ; ++qq) loc[qq][i] = dot[qq] * scale;
    }

    // ---- row max reduction (all TQ rows in parallel) ----
#pragma unroll
    for (int qq = 0; qq < TQ; ++qq) {
        float lm = loc[qq][0];
#pragma unroll
        for (int i = 1; i < 8; ++i) lm = fmaxf(lm, loc[qq][i]);
        red[qq][tid] = lm;
    }
    __syncthreads();
    for (int st = 128; st > 0; st >>= 1) {
        if (tid < st) {
#pragma unroll
            for (int qq = 0; qq < TQ; ++qq)
                red[qq][tid] = fmaxf(red[qq][tid], red[qq][tid + st]);
        }
        __syncthreads();
    }
    if (tid < TQ) mrow[tid] = red[tid][0];
    __syncthreads();

    // ---- exp + sum reduction ----
#pragma unroll
    for (int qq = 0; qq < TQ; ++qq) {
        const float m = mrow[qq];
        float ls = 0.f;
#pragma unroll
        for (int i = 0; i < 8; ++i) {
            const float e = __expf(loc[qq][i] - m);
            loc[qq][i] = e;
            sc[qq][i * 256 + tid] = e;
            ls += e;
        }
        red[qq][tid] = ls;
    }
    __syncthreads();
    for (int st = 128; st > 0; st >>= 1) {
        if (tid < st) {
#pragma unroll
            for (int qq = 0; qq < TQ; ++qq)
                red[qq][tid] += red[qq][tid + st];
        }
        __syncthreads();
    }
    if (tid < TQ) srow[tid] = red[tid][0];
    __syncthreads();

    // ---- write normalized attn (coalesced) ----
#pragma unroll
    for (int qq = 0; qq < TQ; ++qq) {
        const float inv = 1.0f / srow[qq];
        const size_t base = (((size_t)(b * NUM_HEADS + h)) * SEQ + (q0 + qq)) * SEQ;
#pragma unroll
        for (int i = 0; i < 8; ++i)
            attn[base + i * 256 + tid] = loc[qq][i] * inv;
    }

    // ---- fused PV: out[qq][d] = sum_k attn[qq][k] * V[k][d] ----
    const int g = tid >> 6;     // k-chunk group 0..3
    const int d = tid & 63;     // output dim
    float acc[TQ] = {0.f, 0.f, 0.f, 0.f};
    const float* Vb = Vp + ((size_t)(b * SEQ)) * D_MODEL + h * 64 + d;
    for (int k = g * 512; k < (g + 1) * 512; ++k) {
        const float v = Vb[(size_t)k * D_MODEL];
#pragma unroll
        for (int qq = 0; qq < TQ; ++qq) acc[qq] += sc[qq][k] * v;
    }
    __syncthreads();   // red[] reuse
#pragma unroll
    for (int qq = 0; qq < TQ; ++qq) red[qq][tid] = acc[qq];
    __syncthreads();
    if (tid < 64) {
#pragma unroll
        for (int qq = 0; qq < TQ; ++qq) {
            const float s = red[qq][tid] + red[qq][tid + 64] +
                            red[qq][tid + 128] + red[qq][tid + 192];
            ctx[((size_t)(b * SEQ + q0 + qq)) * D_MODEL + h * 64 + tid] = s / srow[qq];
        }
    }
}

// ---------------------------------------------------------------------------
extern "C" void kernel_launch(void* const* d_in, const int* in_sizes, int n_in,
                              void* d_out, int out_size, void* d_ws, size_t ws_size,
                              hipStream_t stream) {
    const float* query = (const float*)d_in[0];
    const float* key   = (const float*)d_in[1];
    const float* value = (const float*)d_in[2];
    const float* Wq = (const float*)d_in[3];
    const float* bq = (const float*)d_in[4];
    const float* Wk = (const float*)d_in[5];
    const float* bk = (const float*)d_in[6];
    const float* Wv = (const float*)d_in[7];
    const float* bv = (const float*)d_in[8];
    const float* Wo = (const float*)d_in[9];
    const float* bo = (const float*)d_in[10];

    float* out  = (float*)d_out;                               // [B,S,D]
    float* attn = out + (size_t)BATCH * SEQ * D_MODEL;         // [B,H,S,S]

    const size_t MAT = (size_t)BATCH * SEQ * D_MODEL;          // 4096*1024
    float* ws  = (float*)d_ws;
    float* Qp  = ws;
    float* Kp  = Qp + MAT;
    float* Vp  = Kp + MAT;
    float* ctx = Vp + MAT;

    const int M = BATCH * SEQ;                                 // 4096
    dim3 gblk(256), ggrid(D_MODEL / 64, M / 64);

    gemm_bias_kernel<<<ggrid, gblk, 0, stream>>>(query, Wq, bq, Qp);
    gemm_bias_kernel<<<ggrid, gblk, 0, stream>>>(key,   Wk, bk, Kp);
    gemm_bias_kernel<<<ggrid, gblk, 0, stream>>>(value, Wv, bv, Vp);

    dim3 agrid(SEQ / TQ, NUM_HEADS, BATCH);
    attn_kernel<<<agrid, 256, 0, stream>>>(Qp, Kp, Vp, attn, ctx);

    gemm_bias_kernel<<<ggrid, gblk, 0, stream>>>(ctx, Wo, bo, out);
}